// Round 8
// baseline (600.288 us; speedup 1.0000x reference)
//
#include <hip/hip_runtime.h>
#include <cmath>

// ---- chunking: SCH=128 tokens/chunk, 4 sub-chunks of 32 (one per wave) ----
// m0 sequences L={21824,5440,1344,320} -> chunks {171,43,11,3} per batch
#define SCH 128
#define SUB 32
#define NCB 228      // chunks per batch: 171+43+11+3
#define NCHUNK 1824  // 8 batches
// ws u32/f32 word offsets (decoupled-lookback state, ~1.06 MB)
#define WS_FLAG 16               // u32[NCHUNK]
#define WS_SD   1840             // f32[NCHUNK*16]
#define WS_H    31024            // u32[NCHUNK*128] (bf16 pairs over n)
// smem word offsets, m0 path (weights end 1385)
#define SW_IN 0        // 32x8
#define SW_CONVW 256   // 16x4
#define SW_CONVB 320
#define SW_XPROJ 336   // 33x16
#define SW_DTW 864
#define SW_DTB 880
#define SW_A 896       // 16x16  (A = -exp(Alog))
#define SW_D 1152
#define SW_OUTW 1168   // 8x16
#define SW_NG 1296
#define SW_NB 1304
#define SW_PW 1312     // 8x8
#define SW_PB 1376
#define SW_SKIP 1384
// xi (131 rows x 17 fp32, only inside stage1) UNIONs with packed records:
// record = bf16 pairs [dlp8|xcp8|Bp8|Cp8] as u32 words, stride 34
#define REC 1392
#define YOF 5744       // scratch: wave locals (4x272) then y: 128x16 f32
#define SMEM_F 12564   // sized for c5 path union; 50,256 B (LDS size is perf-neutral here, R6->R7)
// c5 (m1) path offsets
#define V_IN 0
#define V_CONVW 1024
#define V_CONVB 1152
#define V_XPROJ 1184
#define V_DTW 2240
#define V_DTB 2272
#define V_A 2304
#define V_D 2816
#define V_OUTW 2848
#define V_NG 3360
#define V_NB 3376
#define V_PW 3392
#define V_PB 3648
#define V_SKIP 3664
#define V_XI 3668      // 64x33
#define V_XC 5780      // 64x33
#define V_DL 7892      // 64x33
#define V_BM 10004     // 64x20
#define V_CM 11284     // 64x20 (ends 12564)

struct Params {
  const float *t0, *t1, *t2, *t3, *t4;
  const float *in_w0,*conv_w0,*conv_b0,*xproj0,*dtw0,*dtb0,*Alog0,*D0,*outw0;
  const float *in_w1,*conv_w1,*conv_b1,*xproj1,*dtw1,*dtb1,*Alog1,*D1,*outw1;
  const float *ng,*nb,*pw,*pb,*n1g,*n1b,*p1w,*p1b,*skip;
  float* out;
  unsigned* wsu;   // ws as u32 (ticket @0, flags, packed h)
  float* wsf;      // ws as f32 (sumdelta)
};

__device__ __forceinline__ float softplusf(float x) { return x > 20.f ? x : log1pf(__expf(x)); }
__device__ __forceinline__ float siluf(float x) { return x * (1.f / (1.f + __expf(-x))); }
__device__ __forceinline__ void st4(float* p4, float a, float b, float c, float d) {
  float4 v; v.x = a; v.y = b; v.z = c; v.w = d; *(float4*)p4 = v;
}
// bf16 pair pack/unpack
__device__ __forceinline__ unsigned pk(float a, float b) {
  unsigned ua = __float_as_uint(a) + 0x8000u;
  unsigned ub = __float_as_uint(b) + 0x8000u;
  return (ua >> 16) | (ub & 0xFFFF0000u);
}
__device__ __forceinline__ float lo16(unsigned w) { return __uint_as_float(w << 16); }
__device__ __forceinline__ float hi16(unsigned w) { return __uint_as_float(w & 0xFFFF0000u); }

struct Loc { int k, pos, ch, hw, C; };

__device__ __forceinline__ Loc locate(int seq, int l) {
  Loc r;
  if (seq == 0) { r.ch = 0;
    if (l < 16384)      { r.k=0; r.pos=l;        r.hw=16384; r.C=8;  }
    else if (l < 20480) { r.k=1; r.pos=l-16384;  r.hw=4096;  r.C=16; }
    else if (l < 21504) { r.k=2; r.pos=l-20480;  r.hw=1024;  r.C=24; }
    else if (l < 21760) { r.k=3; r.pos=l-21504;  r.hw=256;   r.C=32; }
    else                { r.k=4; r.pos=l-21760;  r.hw=64;    r.C=48; }
  } else if (seq == 1) { r.ch = 8;
    if (l < 4096)       { r.k=1; r.pos=l;        r.hw=4096;  r.C=16; }
    else if (l < 5120)  { r.k=2; r.pos=l-4096;   r.hw=1024;  r.C=24; }
    else if (l < 5376)  { r.k=3; r.pos=l-5120;   r.hw=256;   r.C=32; }
    else                { r.k=4; r.pos=l-5376;   r.hw=64;    r.C=48; }
  } else if (seq == 2) { r.ch = 16;
    if (l < 1024)       { r.k=2; r.pos=l;        r.hw=1024;  r.C=24; }
    else if (l < 1280)  { r.k=3; r.pos=l-1024;   r.hw=256;   r.C=32; }
    else                { r.k=4; r.pos=l-1280;   r.hw=64;    r.C=48; }
  } else { r.ch = 24;
    if (l < 256)        { r.k=3; r.pos=l;        r.hw=256;   r.C=32; }
    else                { r.k=4; r.pos=l-256;    r.hw=64;    r.C=48; }
  }
  return r;
}

__device__ __forceinline__ const float* tsel(const Params& p, int k) {
  switch (k) { case 0: return p.t0; case 1: return p.t1; case 2: return p.t2;
               case 3: return p.t3; default: return p.t4; }
}
__device__ __forceinline__ int outbase(int k) {
  switch (k) { case 0: return 0; case 1: return 1048576; case 2: return 1572864;
               case 3: return 1769472; default: return 1835008; }
}

__device__ __forceinline__ void gather8(const Params& p, int b, int seq, int l, float* c) {
  Loc lc = locate(seq, l);
  const float* t = tsel(p, lc.k);
  int base = (b * lc.C + lc.ch) * lc.hw + lc.pos;
  #pragma unroll
  for (int j = 0; j < 8; ++j) c[j] = t[base + j * lc.hw];
}

__device__ __forceinline__ void decode_bid(int bid, int& b, int& seq, int& l0, int& Sa) {
  b = bid / NCB;
  int r = bid - b * NCB;
  int c, L;
  if (r < 171)      { seq = 0; c = r;       L = 21824; }
  else if (r < 214) { seq = 1; c = r - 171; L = 5440;  }
  else if (r < 225) { seq = 2; c = r - 214; L = 1344;  }
  else              { seq = 3; c = r - 225; L = 320;   }
  l0 = c * SCH;
  int rem = L - l0;
  Sa = rem < SCH ? rem : SCH;   // always 128 or 64
}

__device__ void load_w0(const Params& p, float* s, int tid) {
  for (int i = tid; i < 256; i += 256) s[SW_IN + i] = p.in_w0[i];
  for (int i = tid; i < 64;  i += 256) s[SW_CONVW + i] = p.conv_w0[i];
  for (int i = tid; i < 16;  i += 256) s[SW_CONVB + i] = p.conv_b0[i];
  for (int i = tid; i < 528; i += 256) s[SW_XPROJ + i] = p.xproj0[i];
  for (int i = tid; i < 16;  i += 256) s[SW_DTW + i] = p.dtw0[i];
  for (int i = tid; i < 16;  i += 256) s[SW_DTB + i] = p.dtb0[i];
  for (int i = tid; i < 256; i += 256) s[SW_A + i] = -__expf(p.Alog0[i]);
  for (int i = tid; i < 16;  i += 256) s[SW_D + i] = p.D0[i];
  for (int i = tid; i < 128; i += 256) s[SW_OUTW + i] = p.outw0[i];
  for (int i = tid; i < 8;   i += 256) s[SW_NG + i] = p.ng[i];
  for (int i = tid; i < 8;   i += 256) s[SW_NB + i] = p.nb[i];
  for (int i = tid; i < 64;  i += 256) s[SW_PW + i] = p.pw[i];
  for (int i = tid; i < 8;   i += 256) s[SW_PB + i] = p.pb[i];
  if (tid == 0) s[SW_SKIP] = p.skip[0];
}

// chunk front end (runs ONCE): xi fp32 (stride 17) unions with record region;
// emits bf16-pair records [dl8|xc8|B8|C8] stride 34. Rows >= Sa zeroed.
__device__ void stage1(const Params& p, float* s, int b, int seq, int l0, int Sa, int tid) {
  if (tid < Sa + 3) {
    int l = l0 - 3 + tid;
    float x8[8];
    if (l >= 0) gather8(p, b, seq, l, x8);
    else {
      #pragma unroll
      for (int j = 0; j < 8; ++j) x8[j] = 0.f;
    }
    #pragma unroll
    for (int i = 0; i < 16; ++i) {
      float a = 0.f;
      #pragma unroll
      for (int j = 0; j < 8; ++j) a = fmaf(s[SW_IN + i * 8 + j], x8[j], a);
      s[REC + tid * 17 + i] = a;
    }
  }
  __syncthreads();
  float xc[16];
  float dt = 0.f;
  bool act = tid < Sa;
  if (act) {
    #pragma unroll
    for (int i = 0; i < 16; ++i) {
      float a = s[SW_CONVB + i];
      #pragma unroll
      for (int kk = 0; kk < 4; ++kk)
        a = fmaf(s[SW_CONVW + i * 4 + kk], s[REC + (tid + kk) * 17 + i], a);
      xc[i] = siluf(a);
      dt = fmaf(s[SW_XPROJ + i], xc[i], dt);
    }
  }
  __syncthreads();
  unsigned* ru = (unsigned*)&s[REC + tid * 34];
  if (act) {
    #pragma unroll
    for (int j = 0; j < 8; ++j) {
      float a0 = softplusf(fmaf(dt, s[SW_DTW + 2*j],     s[SW_DTB + 2*j]));
      float a1 = softplusf(fmaf(dt, s[SW_DTW + 2*j + 1], s[SW_DTB + 2*j + 1]));
      ru[j] = pk(a0, a1);
    }
    #pragma unroll
    for (int j = 0; j < 8; ++j) ru[8 + j] = pk(xc[2*j], xc[2*j + 1]);
    #pragma unroll
    for (int j = 0; j < 8; ++j) {
      float a0 = 0.f, a1 = 0.f;
      #pragma unroll
      for (int i = 0; i < 16; ++i) {
        a0 = fmaf(s[SW_XPROJ + (1 + 2*j) * 16 + i], xc[i], a0);
        a1 = fmaf(s[SW_XPROJ + (2 + 2*j) * 16 + i], xc[i], a1);
      }
      ru[16 + j] = pk(a0, a1);
    }
    #pragma unroll
    for (int j = 0; j < 8; ++j) {
      float a0 = 0.f, a1 = 0.f;
      #pragma unroll
      for (int i = 0; i < 16; ++i) {
        a0 = fmaf(s[SW_XPROJ + (17 + 2*j) * 16 + i], xc[i], a0);
        a1 = fmaf(s[SW_XPROJ + (18 + 2*j) * 16 + i], xc[i], a1);
      }
      ru[24 + j] = pk(a0, a1);
    }
  } else if (tid < SCH) {
    #pragma unroll
    for (int j = 0; j < 32; ++j) ru[j] = 0u;
  }
  __syncthreads();
}

// ---- c5 / m1 path (fp32, one block per batch; tickets 0..7) ----
__device__ void load_w1(const Params& p, float* s, int tid) {
  for (int i = tid; i < 1024; i += 256) s[V_IN + i] = p.in_w1[i];
  for (int i = tid; i < 128;  i += 256) s[V_CONVW + i] = p.conv_w1[i];
  for (int i = tid; i < 32;   i += 256) s[V_CONVB + i] = p.conv_b1[i];
  for (int i = tid; i < 1056; i += 256) s[V_XPROJ + i] = p.xproj1[i];
  for (int i = tid; i < 32;   i += 256) s[V_DTW + i] = p.dtw1[i];
  for (int i = tid; i < 32;   i += 256) s[V_DTB + i] = p.dtb1[i];
  for (int i = tid; i < 512;  i += 256) s[V_A + i] = -__expf(p.Alog1[i]);
  for (int i = tid; i < 32;   i += 256) s[V_D + i] = p.D1[i];
  for (int i = tid; i < 512;  i += 256) s[V_OUTW + i] = p.outw1[i];
  for (int i = tid; i < 16;   i += 256) s[V_NG + i] = p.n1g[i];
  for (int i = tid; i < 16;   i += 256) s[V_NB + i] = p.n1b[i];
  for (int i = tid; i < 256;  i += 256) s[V_PW + i] = p.p1w[i];
  for (int i = tid; i < 16;   i += 256) s[V_PB + i] = p.p1b[i];
  if (tid == 0) s[V_SKIP] = p.skip[0];
}

__device__ void c5_path(const Params& p, float* s, int b, int tid) {
  load_w1(p, s, tid);
  __syncthreads();
  float x16[16];
  bool act = tid < 64;
  if (act) {
    #pragma unroll
    for (int j = 0; j < 16; ++j) x16[j] = p.t4[(b * 48 + 32 + j) * 64 + tid];
    #pragma unroll
    for (int i = 0; i < 32; ++i) {
      float a = 0.f;
      #pragma unroll
      for (int j = 0; j < 16; ++j) a = fmaf(s[V_IN + i * 16 + j], x16[j], a);
      s[V_XI + tid * 33 + i] = a;
    }
  }
  __syncthreads();
  if (act) {
    float xc[32];
    #pragma unroll
    for (int i = 0; i < 32; ++i) {
      float a = s[V_CONVB + i];
      #pragma unroll
      for (int kk = 0; kk < 4; ++kk) {
        int r = tid + kk - 3;
        if (r >= 0) a = fmaf(s[V_CONVW + i * 4 + kk], s[V_XI + r * 33 + i], a);
      }
      xc[i] = siluf(a);
      s[V_XC + tid * 33 + i] = xc[i];
    }
    float dt = 0.f;
    #pragma unroll
    for (int i = 0; i < 32; ++i) dt = fmaf(s[V_XPROJ + i], xc[i], dt);
    #pragma unroll
    for (int n = 0; n < 16; ++n) {
      float a = 0.f, c = 0.f;
      #pragma unroll
      for (int i = 0; i < 32; ++i) {
        a = fmaf(s[V_XPROJ + (1 + n) * 32 + i], xc[i], a);
        c = fmaf(s[V_XPROJ + (17 + n) * 32 + i], xc[i], c);
      }
      s[V_BM + tid * 20 + n] = a;
      s[V_CM + tid * 20 + n] = c;
    }
    #pragma unroll
    for (int d = 0; d < 32; ++d)
      s[V_DL + tid * 33 + d] = softplusf(fmaf(dt, s[V_DTW + d], s[V_DTB + d]));
  }
  __syncthreads();
  if (tid < 128) {
    int d = tid >> 2, ng = tid & 3;
    float4 Av = *(float4*)&s[V_A + d * 16 + ng * 4];
    float h0 = 0.f, h1 = 0.f, h2 = 0.f, h3 = 0.f;
    for (int tile = 0; tile < 16; ++tile) {
      int tb = tile * 4;
      float dl[4], xv[4]; float4 bm[4], cm[4];
      #pragma unroll
      for (int i = 0; i < 4; ++i) {
        dl[i] = s[V_DL + (tb + i) * 33 + d];
        xv[i] = s[V_XC + (tb + i) * 33 + d];
        bm[i] = *(float4*)&s[V_BM + (tb + i) * 20 + ng * 4];
        cm[i] = *(float4*)&s[V_CM + (tb + i) * 20 + ng * 4];
      }
      float yp[4];
      #pragma unroll
      for (int i = 0; i < 4; ++i) {
        float u = dl[i] * xv[i];
        float e0 = __expf(Av.x * dl[i]), e1 = __expf(Av.y * dl[i]);
        float e2 = __expf(Av.z * dl[i]), e3 = __expf(Av.w * dl[i]);
        h0 = fmaf(e0, h0, u * bm[i].x);
        h1 = fmaf(e1, h1, u * bm[i].y);
        h2 = fmaf(e2, h2, u * bm[i].z);
        h3 = fmaf(e3, h3, u * bm[i].w);
        float y = h0 * cm[i].x;
        y = fmaf(h1, cm[i].y, y); y = fmaf(h2, cm[i].z, y); y = fmaf(h3, cm[i].w, y);
        yp[i] = y;
      }
      #pragma unroll
      for (int i = 0; i < 4; ++i) yp[i] += __shfl_xor(yp[i], 1);
      #pragma unroll
      for (int i = 0; i < 4; ++i) yp[i] += __shfl_xor(yp[i], 2);
      float ysel = ng == 0 ? yp[0] : ng == 1 ? yp[1] : ng == 2 ? yp[2] : yp[3];
      s[V_DL + (tb + ng) * 33 + d] = ysel;
    }
  }
  __syncthreads();
  if (act) {
    float y[32];
    #pragma unroll
    for (int d = 0; d < 32; ++d) {
      float z = 0.f;
      #pragma unroll
      for (int j = 0; j < 16; ++j) z = fmaf(s[V_IN + (32 + d) * 16 + j], x16[j], z);
      y[d] = (s[V_DL + tid * 33 + d] + s[V_XC + tid * 33 + d] * s[V_D + d]) * siluf(z);
    }
    float o[16];
    float sk = s[V_SKIP];
    #pragma unroll
    for (int m = 0; m < 16; ++m) {
      float a = 0.f;
      #pragma unroll
      for (int d = 0; d < 32; ++d) a = fmaf(s[V_OUTW + m * 32 + d], y[d], a);
      o[m] = a + sk * x16[m];
    }
    float mu = 0.f;
    #pragma unroll
    for (int m = 0; m < 16; ++m) mu += o[m];
    mu *= (1.f / 16.f);
    float var = 0.f;
    #pragma unroll
    for (int m = 0; m < 16; ++m) { float t = o[m] - mu; var += t * t; }
    var *= (1.f / 16.f);
    float inv = rsqrtf(var + 1e-5f);
    float ln[16];
    #pragma unroll
    for (int m = 0; m < 16; ++m) ln[m] = (o[m] - mu) * inv * s[V_NG + m] + s[V_NB + m];
    #pragma unroll
    for (int m = 0; m < 16; ++m) {
      float a = s[V_PB + m];
      #pragma unroll
      for (int j = 0; j < 16; ++j) a = fmaf(s[V_PW + m * 16 + j], ln[j], a);
      p.out[1835008 + (b * 48 + 32 + m) * 64 + tid] = a;
    }
  }
}

// ===== single fused kernel: stage1 once + local scan + decoupled lookback +
//       rescan-with-y + fused epilogue.  Ticket => dispatch-ordered virtual id.
__global__ __launch_bounds__(256) void k_fused(Params p) {
  __shared__ float s[SMEM_F];
  __shared__ int vb_sh;
  int tid = threadIdx.x;
  if (tid == 0) vb_sh = (int)atomicAdd(&p.wsu[0], 1u);
  __syncthreads();
  int vb = vb_sh;
  if (vb < 8) { c5_path(p, s, vb, tid); return; }
  int cid = vb - 8;
  int b, seq, l0, Sa;
  decode_bid(cid, b, seq, l0, Sa);
  load_w0(p, s, tid);
  __syncthreads();
  stage1(p, s, b, seq, l0, Sa, tid);

  int w = tid >> 6, lane = tid & 63;
  int d = lane >> 2, ng = lane & 3;
  int dh = d >> 1;
  bool dodd = d & 1;
  float4 Av = *(float4*)&s[SW_A + d * 16 + ng * 4];
  const unsigned* su = (const unsigned*)s;
  int t0 = w * SUB;

  // ---- local scan (h from 0) over this wave's sub-chunk ----
  float h0 = 0.f, h1 = 0.f, h2 = 0.f, h3 = 0.f, sd = 0.f;
  for (int tile = 0; tile < 8; ++tile) {
    int tb = t0 + tile * 4;
    float dl[4], u[4], b0[4], b1[4], b2[4], b3[4];
    #pragma unroll
    for (int i = 0; i < 4; ++i) {
      int base = REC + (tb + i) * 34;
      unsigned wd = su[base + dh];
      unsigned wx = su[base + 8 + dh];
      unsigned wB0 = su[base + 16 + ng * 2];
      unsigned wB1 = su[base + 16 + ng * 2 + 1];
      dl[i] = dodd ? hi16(wd) : lo16(wd);
      u[i] = dl[i] * (dodd ? hi16(wx) : lo16(wx));
      b0[i] = lo16(wB0); b1[i] = hi16(wB0); b2[i] = lo16(wB1); b3[i] = hi16(wB1);
    }
    #pragma unroll
    for (int i = 0; i < 4; ++i) {
      float e0 = __expf(Av.x * dl[i]), e1 = __expf(Av.y * dl[i]);
      float e2 = __expf(Av.z * dl[i]), e3 = __expf(Av.w * dl[i]);
      h0 = fmaf(e0, h0, u[i] * b0[i]);
      h1 = fmaf(e1, h1, u[i] * b1[i]);
      h2 = fmaf(e2, h2, u[i] * b2[i]);
      h3 = fmaf(e3, h3, u[i] * b3[i]);
      sd += dl[i];
    }
  }
  // ---- wave locals -> LDS scratch (YOF region, consumed before y) ----
  st4(&s[YOF + w * 272 + d * 16 + ng * 4], h0, h1, h2, h3);
  if (ng == 0) s[YOF + w * 272 + 256 + d] = sd;
  __syncthreads();
  // ---- chunk-level local transform (compose 4 waves, forward) ----
  float S = 0.f, C0 = 0.f, C1 = 0.f, C2 = 0.f, C3 = 0.f;
  #pragma unroll
  for (int ww = 0; ww < 4; ++ww) {
    float sdw = s[YOF + ww * 272 + 256 + d];
    float4 hw = *(float4*)&s[YOF + ww * 272 + d * 16 + ng * 4];
    float e0 = __expf(Av.x * sdw), e1 = __expf(Av.y * sdw);
    float e2 = __expf(Av.z * sdw), e3 = __expf(Av.w * sdw);
    C0 = fmaf(e0, C0, hw.x); C1 = fmaf(e1, C1, hw.y);
    C2 = fmaf(e2, C2, hw.z); C3 = fmaf(e3, C3, hw.w);
    S += sdw;
  }
  // ---- publish (device-scope atomic stores; release flag) ----
  if (w == 0) {
    __hip_atomic_store(&p.wsu[WS_H + cid * 128 + d * 8 + ng * 2], pk(C0, C1),
                       __ATOMIC_RELAXED, __HIP_MEMORY_SCOPE_AGENT);
    __hip_atomic_store(&p.wsu[WS_H + cid * 128 + d * 8 + ng * 2 + 1], pk(C2, C3),
                       __ATOMIC_RELAXED, __HIP_MEMORY_SCOPE_AGENT);
    if (ng == 0)
      __hip_atomic_store(&p.wsf[WS_SD + cid * 16 + d], S,
                         __ATOMIC_RELAXED, __HIP_MEMORY_SCOPE_AGENT);
  }
  __syncthreads();
  if (tid == 0)
    __hip_atomic_store(&p.wsu[WS_FLAG + cid], 1u,
                       __ATOMIC_RELEASE, __HIP_MEMORY_SCOPE_AGENT);
  // ---- decoupled lookback: compose predecessors back to strip start ----
  int strip_first = cid - (l0 >> 7);
  float Sacc = 0.f, Hs0 = 0.f, Hs1 = 0.f, Hs2 = 0.f, Hs3 = 0.f;
  int j = cid - 1;
  while (j >= strip_first) {
    int nb = j - strip_first + 1;
    if (nb > 16) nb = 16;
    if (tid < nb) {
      while (__hip_atomic_load(&p.wsu[WS_FLAG + (j - tid)],
                               __ATOMIC_ACQUIRE, __HIP_MEMORY_SCOPE_AGENT) == 0u)
        __builtin_amdgcn_s_sleep(16);
    }
    __syncthreads();
    unsigned wa[16], wb[16]; float sdv[16];
    for (int i = 0; i < nb; ++i) {
      int jj = j - i;
      wa[i] = __hip_atomic_load(&p.wsu[WS_H + jj * 128 + d * 8 + ng * 2],
                                __ATOMIC_RELAXED, __HIP_MEMORY_SCOPE_AGENT);
      wb[i] = __hip_atomic_load(&p.wsu[WS_H + jj * 128 + d * 8 + ng * 2 + 1],
                                __ATOMIC_RELAXED, __HIP_MEMORY_SCOPE_AGENT);
      sdv[i] = __hip_atomic_load(&p.wsf[WS_SD + jj * 16 + d],
                                 __ATOMIC_RELAXED, __HIP_MEMORY_SCOPE_AGENT);
    }
    for (int i = 0; i < nb; ++i) {   // prepend earlier segment A to accum B
      float e0 = __expf(Av.x * Sacc), e1 = __expf(Av.y * Sacc);
      float e2 = __expf(Av.z * Sacc), e3 = __expf(Av.w * Sacc);
      Hs0 = fmaf(e0, lo16(wa[i]), Hs0);
      Hs1 = fmaf(e1, hi16(wa[i]), Hs1);
      Hs2 = fmaf(e2, lo16(wb[i]), Hs2);
      Hs3 = fmaf(e3, hi16(wb[i]), Hs3);
      Sacc += sdv[i];
    }
    j -= nb;
  }
  // ---- this wave's true h_start = (waves<w) forward-composed on chunk start
  float g0 = Hs0, g1 = Hs1, g2 = Hs2, g3 = Hs3;
  for (int ww = 0; ww < w; ++ww) {
    float sdw = s[YOF + ww * 272 + 256 + d];
    float4 hw = *(float4*)&s[YOF + ww * 272 + d * 16 + ng * 4];
    float e0 = __expf(Av.x * sdw), e1 = __expf(Av.y * sdw);
    float e2 = __expf(Av.z * sdw), e3 = __expf(Av.w * sdw);
    g0 = fmaf(e0, g0, hw.x); g1 = fmaf(e1, g1, hw.y);
    g2 = fmaf(e2, g2, hw.z); g3 = fmaf(e3, g3, hw.w);
  }
  __syncthreads();   // scratch consumed; YOF becomes y region
  // ---- full rescan with y ----
  h0 = g0; h1 = g1; h2 = g2; h3 = g3;
  for (int tile = 0; tile < 8; ++tile) {
    int tb = t0 + tile * 4;
    float dl[4], u[4], b0[4], b1[4], b2[4], b3[4], c0[4], c1[4], c2[4], c3[4];
    #pragma unroll
    for (int i = 0; i < 4; ++i) {
      int base = REC + (tb + i) * 34;
      unsigned wd = su[base + dh];
      unsigned wx = su[base + 8 + dh];
      unsigned wB0 = su[base + 16 + ng * 2];
      unsigned wB1 = su[base + 16 + ng * 2 + 1];
      unsigned wC0 = su[base + 24 + ng * 2];
      unsigned wC1 = su[base + 24 + ng * 2 + 1];
      dl[i] = dodd ? hi16(wd) : lo16(wd);
      u[i] = dl[i] * (dodd ? hi16(wx) : lo16(wx));
      b0[i] = lo16(wB0); b1[i] = hi16(wB0); b2[i] = lo16(wB1); b3[i] = hi16(wB1);
      c0[i] = lo16(wC0); c1[i] = hi16(wC0); c2[i] = lo16(wC1); c3[i] = hi16(wC1);
    }
    float yp[4];
    #pragma unroll
    for (int i = 0; i < 4; ++i) {
      float e0 = __expf(Av.x * dl[i]), e1 = __expf(Av.y * dl[i]);
      float e2 = __expf(Av.z * dl[i]), e3 = __expf(Av.w * dl[i]);
      h0 = fmaf(e0, h0, u[i] * b0[i]);
      h1 = fmaf(e1, h1, u[i] * b1[i]);
      h2 = fmaf(e2, h2, u[i] * b2[i]);
      h3 = fmaf(e3, h3, u[i] * b3[i]);
      float y = h0 * c0[i];
      y = fmaf(h1, c1[i], y); y = fmaf(h2, c2[i], y); y = fmaf(h3, c3[i], y);
      yp[i] = y;
    }
    #pragma unroll
    for (int i = 0; i < 4; ++i) yp[i] += __shfl_xor(yp[i], 1);
    #pragma unroll
    for (int i = 0; i < 4; ++i) yp[i] += __shfl_xor(yp[i], 2);
    float ysel = ng == 0 ? yp[0] : ng == 1 ? yp[1] : ng == 2 ? yp[2] : yp[3];
    s[YOF + (tb + ng) * 16 + d] = ysel;
  }
  __syncthreads();
  // ---- fused epilogue: gate + out-proj + skip + LN + proj + scatter ----
  if (tid < Sa) {
    int l = l0 + tid;
    float c8[8];
    gather8(p, b, seq, l, c8);
    const unsigned* ru = (const unsigned*)&s[REC + tid * 34];
    float xcv[16];
    #pragma unroll
    for (int j2 = 0; j2 < 8; ++j2) {
      unsigned wv = ru[8 + j2];
      xcv[2*j2] = lo16(wv); xcv[2*j2 + 1] = hi16(wv);
    }
    float y[16];
    #pragma unroll
    for (int i = 0; i < 16; ++i) {
      float z = 0.f;
      #pragma unroll
      for (int j2 = 0; j2 < 8; ++j2) z = fmaf(s[SW_IN + (16 + i) * 8 + j2], c8[j2], z);
      y[i] = (s[YOF + tid * 16 + i] + xcv[i] * s[SW_D + i]) * siluf(z);
    }
    float o[8];
    float sk = s[SW_SKIP];
    #pragma unroll
    for (int m = 0; m < 8; ++m) {
      float a = 0.f;
      #pragma unroll
      for (int dd = 0; dd < 16; ++dd) a = fmaf(s[SW_OUTW + m * 16 + dd], y[dd], a);
      o[m] = a + sk * c8[m];
    }
    float mu = 0.f;
    #pragma unroll
    for (int m = 0; m < 8; ++m) mu += o[m];
    mu *= 0.125f;
    float var = 0.f;
    #pragma unroll
    for (int m = 0; m < 8; ++m) { float t = o[m] - mu; var += t * t; }
    var *= 0.125f;
    float inv = rsqrtf(var + 1e-5f);
    float ln[8];
    #pragma unroll
    for (int m = 0; m < 8; ++m) ln[m] = (o[m] - mu) * inv * s[SW_NG + m] + s[SW_NB + m];
    Loc lc = locate(seq, l);
    int obase = outbase(lc.k) + (b * lc.C + lc.ch) * lc.hw + lc.pos;
    #pragma unroll
    for (int m = 0; m < 8; ++m) {
      float a = s[SW_PB + m];
      #pragma unroll
      for (int j2 = 0; j2 < 8; ++j2) a = fmaf(s[SW_PW + m * 8 + j2], ln[j2], a);
      p.out[obase + m * lc.hw] = a;
    }
  }
}

extern "C" void kernel_launch(void* const* d_in, const int* in_sizes, int n_in,
                              void* d_out, int out_size, void* d_ws, size_t ws_size,
                              hipStream_t stream) {
  (void)in_sizes; (void)n_in; (void)out_size; (void)ws_size;
  Params p;
  p.t0 = (const float*)d_in[0];  p.t1 = (const float*)d_in[1];
  p.t2 = (const float*)d_in[2];  p.t3 = (const float*)d_in[3];
  p.t4 = (const float*)d_in[4];
  p.in_w0   = (const float*)d_in[5];
  p.conv_w0 = (const float*)d_in[6];
  p.conv_b0 = (const float*)d_in[7];
  p.xproj0  = (const float*)d_in[8];
  p.dtw0    = (const float*)d_in[9];
  p.dtb0    = (const float*)d_in[10];
  p.Alog0   = (const float*)d_in[11];
  p.D0      = (const float*)d_in[12];
  p.outw0   = (const float*)d_in[13];
  p.in_w1   = (const float*)d_in[14];
  p.conv_w1 = (const float*)d_in[15];
  p.conv_b1 = (const float*)d_in[16];
  p.xproj1  = (const float*)d_in[17];
  p.dtw1    = (const float*)d_in[18];
  p.dtb1    = (const float*)d_in[19];
  p.Alog1   = (const float*)d_in[20];
  p.D1      = (const float*)d_in[21];
  p.outw1   = (const float*)d_in[22];
  p.ng  = (const float*)d_in[23];
  p.nb  = (const float*)d_in[24];
  p.pw  = (const float*)d_in[25];
  p.pb  = (const float*)d_in[26];
  p.n1g = (const float*)d_in[27];
  p.n1b = (const float*)d_in[28];
  p.p1w = (const float*)d_in[29];
  p.p1b = (const float*)d_in[30];
  p.skip = (const float*)d_in[31];
  p.out = (float*)d_out;
  p.wsu = (unsigned*)d_ws;
  p.wsf = (float*)d_ws;
  // zero ticket + flags (graph-capture-safe async memset)
  hipMemsetAsync(d_ws, 0, (size_t)(16 + NCHUNK) * 4, stream);
  k_fused<<<dim3(NCHUNK + 8), dim3(256), 0, stream>>>(p);
}

// Round 9
// 401.114 us; speedup vs baseline: 1.4966x; 1.4966x over previous
//
#include <hip/hip_runtime.h>
#include <cmath>

// ---- chunking: SCH=128 tokens/chunk, 4 sub-chunks of 32 (one per wave) ----
// m0 sequences L={21824,5440,1344,320} -> chunks {171,43,11,3} per batch
#define SCH 128
#define SUB 32
#define NCB 228      // chunks per batch: 171+43+11+3
#define NCHUNK 1824  // 8 batches
#define NSUB 7296    // 4*NCHUNK
#define CPB 4        // chunks per block (456 blocks/pass) - amortize per-WG overhead
#define NBLK 456
// smem word offsets, m0 path (weights end 1385)
#define SW_IN 0        // 32x8
#define SW_CONVW 256   // 16x4
#define SW_CONVB 320
#define SW_XPROJ 336   // 33x16
#define SW_DTW 864
#define SW_DTB 880
#define SW_A 896       // 16x16  (A = -exp(Alog))
#define SW_D 1152
#define SW_OUTW 1168   // 8x16
#define SW_NG 1296
#define SW_NB 1304
#define SW_PW 1312     // 8x8
#define SW_PB 1376
#define SW_SKIP 1384
// xi (131 rows x 17 fp32, only inside stage1) UNIONs with the packed records:
// record = bf16 pairs [dlp8|xcp8|Bp8|(Cp8)] as u32 words, stride 26 (p1) / 34 (p3)
#define REC 1392
#define YOF 5744       // pass3 y region: 128 x 16 f32 (REC + 128*34)
#define SMEM1 4720     // 18,880 B
#define SMEM3 7792     // 31,168 B
// c5 (m1) path offsets (inside k_pass2's 12564-word smem)
#define V_IN 0
#define V_CONVW 1024
#define V_CONVB 1152
#define V_XPROJ 1184
#define V_DTW 2240
#define V_DTB 2272
#define V_A 2304
#define V_D 2816
#define V_OUTW 2848
#define V_NG 3360
#define V_NB 3376
#define V_PW 3392
#define V_PB 3648
#define V_SKIP 3664
#define V_XI 3668      // 64x33
#define V_XC 5780      // 64x33
#define V_DL 7892      // 64x33
#define V_BM 10004     // 64x20
#define V_CM 11284     // 64x20 (ends 12564)

struct Params {
  const float *t0, *t1, *t2, *t3, *t4;
  const float *in_w0,*conv_w0,*conv_b0,*xproj0,*dtw0,*dtb0,*Alog0,*D0,*outw0;
  const float *in_w1,*conv_w1,*conv_b1,*xproj1,*dtw1,*dtb1,*Alog1,*D1,*outw1;
  const float *ng,*nb,*pw,*pb,*n1g,*n1b,*p1w,*p1b,*skip;
  float* out;
  float *hloc, *sumdelta;   // hloc = bf16-pair u32 words, 128/sub-chunk (in-place hstart)
};

__device__ __forceinline__ float softplusf(float x) { return x > 20.f ? x : log1pf(__expf(x)); }
__device__ __forceinline__ float siluf(float x) { return x * (1.f / (1.f + __expf(-x))); }
__device__ __forceinline__ unsigned pk(float a, float b) {
  unsigned ua = __float_as_uint(a) + 0x8000u;
  unsigned ub = __float_as_uint(b) + 0x8000u;
  return (ua >> 16) | (ub & 0xFFFF0000u);
}
__device__ __forceinline__ float lo16(unsigned w) { return __uint_as_float(w << 16); }
__device__ __forceinline__ float hi16(unsigned w) { return __uint_as_float(w & 0xFFFF0000u); }

struct Loc { int k, pos, ch, hw, C; };

__device__ __forceinline__ Loc locate(int seq, int l) {
  Loc r;
  if (seq == 0) { r.ch = 0;
    if (l < 16384)      { r.k=0; r.pos=l;        r.hw=16384; r.C=8;  }
    else if (l < 20480) { r.k=1; r.pos=l-16384;  r.hw=4096;  r.C=16; }
    else if (l < 21504) { r.k=2; r.pos=l-20480;  r.hw=1024;  r.C=24; }
    else if (l < 21760) { r.k=3; r.pos=l-21504;  r.hw=256;   r.C=32; }
    else                { r.k=4; r.pos=l-21760;  r.hw=64;    r.C=48; }
  } else if (seq == 1) { r.ch = 8;
    if (l < 4096)       { r.k=1; r.pos=l;        r.hw=4096;  r.C=16; }
    else if (l < 5120)  { r.k=2; r.pos=l-4096;   r.hw=1024;  r.C=24; }
    else if (l < 5376)  { r.k=3; r.pos=l-5120;   r.hw=256;   r.C=32; }
    else                { r.k=4; r.pos=l-5376;   r.hw=64;    r.C=48; }
  } else if (seq == 2) { r.ch = 16;
    if (l < 1024)       { r.k=2; r.pos=l;        r.hw=1024;  r.C=24; }
    else if (l < 1280)  { r.k=3; r.pos=l-1024;   r.hw=256;   r.C=32; }
    else                { r.k=4; r.pos=l-1280;   r.hw=64;    r.C=48; }
  } else { r.ch = 24;
    if (l < 256)        { r.k=3; r.pos=l;        r.hw=256;   r.C=32; }
    else                { r.k=4; r.pos=l-256;    r.hw=64;    r.C=48; }
  }
  return r;
}

__device__ __forceinline__ const float* tsel(const Params& p, int k) {
  switch (k) { case 0: return p.t0; case 1: return p.t1; case 2: return p.t2;
               case 3: return p.t3; default: return p.t4; }
}
// flat offsets of output tensors (with batch dim): total 1859584
__device__ __forceinline__ int outbase(int k) {
  switch (k) { case 0: return 0; case 1: return 1048576; case 2: return 1572864;
               case 3: return 1769472; default: return 1835008; }
}

__device__ __forceinline__ void gather8(const Params& p, int b, int seq, int l, float* c) {
  Loc lc = locate(seq, l);
  const float* t = tsel(p, lc.k);
  int base = (b * lc.C + lc.ch) * lc.hw + lc.pos;
  #pragma unroll
  for (int j = 0; j < 8; ++j) c[j] = t[base + j * lc.hw];
}

__device__ __forceinline__ void decode_bid(int bid, int& b, int& seq, int& l0, int& Sa) {
  b = bid / NCB;
  int r = bid - b * NCB;
  int c, L;
  if (r < 171)      { seq = 0; c = r;       L = 21824; }
  else if (r < 214) { seq = 1; c = r - 171; L = 5440;  }
  else if (r < 225) { seq = 2; c = r - 214; L = 1344;  }
  else              { seq = 3; c = r - 225; L = 320;   }
  l0 = c * SCH;
  int rem = L - l0;
  Sa = rem < SCH ? rem : SCH;   // always 128 or 64
}

__device__ void load_w0(const Params& p, float* s, int tid) {
  for (int i = tid; i < 256; i += 256) s[SW_IN + i] = p.in_w0[i];
  for (int i = tid; i < 64;  i += 256) s[SW_CONVW + i] = p.conv_w0[i];
  for (int i = tid; i < 16;  i += 256) s[SW_CONVB + i] = p.conv_b0[i];
  for (int i = tid; i < 528; i += 256) s[SW_XPROJ + i] = p.xproj0[i];
  for (int i = tid; i < 16;  i += 256) s[SW_DTW + i] = p.dtw0[i];
  for (int i = tid; i < 16;  i += 256) s[SW_DTB + i] = p.dtb0[i];
  for (int i = tid; i < 256; i += 256) s[SW_A + i] = -__expf(p.Alog0[i]);
  for (int i = tid; i < 16;  i += 256) s[SW_D + i] = p.D0[i];
  for (int i = tid; i < 128; i += 256) s[SW_OUTW + i] = p.outw0[i];
  for (int i = tid; i < 8;   i += 256) s[SW_NG + i] = p.ng[i];
  for (int i = tid; i < 8;   i += 256) s[SW_NB + i] = p.nb[i];
  for (int i = tid; i < 64;  i += 256) s[SW_PW + i] = p.pw[i];
  for (int i = tid; i < 8;   i += 256) s[SW_PB + i] = p.pb[i];
  if (tid == 0) s[SW_SKIP] = p.skip[0];
}

// chunk front end: xi fp32 (stride 17) in record region (dead after conv);
// then bf16-pair packed records. Rows >= Sa zeroed => identity scan steps.
template <int RSTR, bool WANT_CM>
__device__ void stage1(const Params& p, float* s, int b, int seq, int l0, int Sa, int tid) {
  if (tid < Sa + 3) {                 // rows r <-> token l0-3+r (conv halo)
    int l = l0 - 3 + tid;
    float x8[8];
    if (l >= 0) gather8(p, b, seq, l, x8);
    else {
      #pragma unroll
      for (int j = 0; j < 8; ++j) x8[j] = 0.f;
    }
    #pragma unroll
    for (int i = 0; i < 16; ++i) {
      float a = 0.f;
      #pragma unroll
      for (int j = 0; j < 8; ++j) a = fmaf(s[SW_IN + i * 8 + j], x8[j], a);
      s[REC + tid * 17 + i] = a;
    }
  }
  __syncthreads();
  float xc[16];
  float dt = 0.f;
  bool act = tid < Sa;
  if (act) {
    #pragma unroll
    for (int i = 0; i < 16; ++i) {
      float a = s[SW_CONVB + i];
      #pragma unroll
      for (int kk = 0; kk < 4; ++kk)
        a = fmaf(s[SW_CONVW + i * 4 + kk], s[REC + (tid + kk) * 17 + i], a);
      xc[i] = siluf(a);
      dt = fmaf(s[SW_XPROJ + i], xc[i], dt);
    }
  }
  __syncthreads();                    // all xi reads done; region becomes records
  unsigned* ru = (unsigned*)&s[REC + tid * RSTR];
  if (act) {
    #pragma unroll
    for (int j = 0; j < 8; ++j) {
      float a0 = softplusf(fmaf(dt, s[SW_DTW + 2*j],     s[SW_DTB + 2*j]));
      float a1 = softplusf(fmaf(dt, s[SW_DTW + 2*j + 1], s[SW_DTB + 2*j + 1]));
      ru[j] = pk(a0, a1);
    }
    #pragma unroll
    for (int j = 0; j < 8; ++j) ru[8 + j] = pk(xc[2*j], xc[2*j + 1]);
    #pragma unroll
    for (int j = 0; j < 8; ++j) {
      float a0 = 0.f, a1 = 0.f;
      #pragma unroll
      for (int i = 0; i < 16; ++i) {
        a0 = fmaf(s[SW_XPROJ + (1 + 2*j) * 16 + i], xc[i], a0);
        a1 = fmaf(s[SW_XPROJ + (2 + 2*j) * 16 + i], xc[i], a1);
      }
      ru[16 + j] = pk(a0, a1);
    }
    if (WANT_CM) {
      #pragma unroll
      for (int j = 0; j < 8; ++j) {
        float a0 = 0.f, a1 = 0.f;
        #pragma unroll
        for (int i = 0; i < 16; ++i) {
          a0 = fmaf(s[SW_XPROJ + (17 + 2*j) * 16 + i], xc[i], a0);
          a1 = fmaf(s[SW_XPROJ + (18 + 2*j) * 16 + i], xc[i], a1);
        }
        ru[24 + j] = pk(a0, a1);
      }
    }
  } else if (tid < SCH) {             // identity (zero) records for padding rows
    #pragma unroll
    for (int j = 0; j < (WANT_CM ? 32 : 24); ++j) ru[j] = 0u;
  }
  __syncthreads();
}

// pass 1: each block does CPB consecutive chunks; local scan -> packed h_local + delta sums
__global__ __launch_bounds__(256) void k_pass1(Params p) {
  __shared__ float s[SMEM1];
  int tid = threadIdx.x;
  load_w0(p, s, tid);
  int w = tid >> 6, lane = tid & 63;
  int d = lane >> 2, ng = lane & 3;
  int dh = d >> 1;
  bool dodd = d & 1;
  int t0 = w * SUB;
  const unsigned* su = (const unsigned*)s;
  for (int it = 0; it < CPB; ++it) {
    int cid = blockIdx.x * CPB + it;
    int b, seq, l0, Sa;
    decode_bid(cid, b, seq, l0, Sa);
    __syncthreads();                 // REC reuse guard (and weights ready on it=0)
    stage1<26, false>(p, s, b, seq, l0, Sa, tid);
    float4 Av = *(float4*)&s[SW_A + d * 16 + ng * 4];
    float h0 = 0.f, h1 = 0.f, h2 = 0.f, h3 = 0.f, sd = 0.f;
    for (int tile = 0; tile < 8; ++tile) {
      int tb = t0 + tile * 4;
      float dl[4], u[4], b0[4], b1[4], b2[4], b3[4];
      #pragma unroll
      for (int i = 0; i < 4; ++i) {
        int base = REC + (tb + i) * 26;
        unsigned wd = su[base + dh];
        unsigned wx = su[base + 8 + dh];
        unsigned wB0 = su[base + 16 + ng * 2];
        unsigned wB1 = su[base + 16 + ng * 2 + 1];
        dl[i] = dodd ? hi16(wd) : lo16(wd);
        u[i] = dl[i] * (dodd ? hi16(wx) : lo16(wx));
        b0[i] = lo16(wB0); b1[i] = hi16(wB0); b2[i] = lo16(wB1); b3[i] = hi16(wB1);
      }
      #pragma unroll
      for (int i = 0; i < 4; ++i) {
        float e0 = __expf(Av.x * dl[i]), e1 = __expf(Av.y * dl[i]);
        float e2 = __expf(Av.z * dl[i]), e3 = __expf(Av.w * dl[i]);
        h0 = fmaf(e0, h0, u[i] * b0[i]);
        h1 = fmaf(e1, h1, u[i] * b1[i]);
        h2 = fmaf(e2, h2, u[i] * b2[i]);
        h3 = fmaf(e3, h3, u[i] * b3[i]);
        sd += dl[i];
      }
    }
    int gs = cid * 4 + w;
    unsigned* hu = (unsigned*)p.hloc;
    hu[gs * 128 + d * 8 + ng * 2]     = pk(h0, h1);
    hu[gs * 128 + d * 8 + ng * 2 + 1] = pk(h2, h3);
    if (ng == 0) p.sumdelta[(size_t)gs * 16 + d] = sd;
  }
}

// ---- c5 / m1 path (fp32; lives in k_pass2's grid) ----
__device__ void load_w1(const Params& p, float* s, int tid) {
  for (int i = tid; i < 1024; i += 256) s[V_IN + i] = p.in_w1[i];
  for (int i = tid; i < 128;  i += 256) s[V_CONVW + i] = p.conv_w1[i];
  for (int i = tid; i < 32;   i += 256) s[V_CONVB + i] = p.conv_b1[i];
  for (int i = tid; i < 1056; i += 256) s[V_XPROJ + i] = p.xproj1[i];
  for (int i = tid; i < 32;   i += 256) s[V_DTW + i] = p.dtw1[i];
  for (int i = tid; i < 32;   i += 256) s[V_DTB + i] = p.dtb1[i];
  for (int i = tid; i < 512;  i += 256) s[V_A + i] = -__expf(p.Alog1[i]);
  for (int i = tid; i < 32;   i += 256) s[V_D + i] = p.D1[i];
  for (int i = tid; i < 512;  i += 256) s[V_OUTW + i] = p.outw1[i];
  for (int i = tid; i < 16;   i += 256) s[V_NG + i] = p.n1g[i];
  for (int i = tid; i < 16;   i += 256) s[V_NB + i] = p.n1b[i];
  for (int i = tid; i < 256;  i += 256) s[V_PW + i] = p.p1w[i];
  for (int i = tid; i < 16;   i += 256) s[V_PB + i] = p.p1b[i];
  if (tid == 0) s[V_SKIP] = p.skip[0];
}

__device__ void c5_path(const Params& p, float* s, int b, int tid) {
  load_w1(p, s, tid);
  __syncthreads();
  float x16[16];
  bool act = tid < 64;
  if (act) {
    #pragma unroll
    for (int j = 0; j < 16; ++j) x16[j] = p.t4[(b * 48 + 32 + j) * 64 + tid];
    #pragma unroll
    for (int i = 0; i < 32; ++i) {
      float a = 0.f;
      #pragma unroll
      for (int j = 0; j < 16; ++j) a = fmaf(s[V_IN + i * 16 + j], x16[j], a);
      s[V_XI + tid * 33 + i] = a;
    }
  }
  __syncthreads();
  if (act) {
    float xc[32];
    #pragma unroll
    for (int i = 0; i < 32; ++i) {
      float a = s[V_CONVB + i];
      #pragma unroll
      for (int kk = 0; kk < 4; ++kk) {
        int r = tid + kk - 3;
        if (r >= 0) a = fmaf(s[V_CONVW + i * 4 + kk], s[V_XI + r * 33 + i], a);
      }
      xc[i] = siluf(a);
      s[V_XC + tid * 33 + i] = xc[i];
    }
    float dt = 0.f;
    #pragma unroll
    for (int i = 0; i < 32; ++i) dt = fmaf(s[V_XPROJ + i], xc[i], dt);
    #pragma unroll
    for (int n = 0; n < 16; ++n) {
      float a = 0.f, c = 0.f;
      #pragma unroll
      for (int i = 0; i < 32; ++i) {
        a = fmaf(s[V_XPROJ + (1 + n) * 32 + i], xc[i], a);
        c = fmaf(s[V_XPROJ + (17 + n) * 32 + i], xc[i], c);
      }
      s[V_BM + tid * 20 + n] = a;
      s[V_CM + tid * 20 + n] = c;
    }
    #pragma unroll
    for (int d = 0; d < 32; ++d)
      s[V_DL + tid * 33 + d] = softplusf(fmaf(dt, s[V_DTW + d], s[V_DTB + d]));
  }
  __syncthreads();
  if (tid < 128) {
    int d = tid >> 2, ng = tid & 3;
    float4 Av = *(float4*)&s[V_A + d * 16 + ng * 4];
    float h0 = 0.f, h1 = 0.f, h2 = 0.f, h3 = 0.f;
    for (int tile = 0; tile < 16; ++tile) {
      int tb = tile * 4;
      float dl[4], xv[4]; float4 bm[4], cm[4];
      #pragma unroll
      for (int i = 0; i < 4; ++i) {
        dl[i] = s[V_DL + (tb + i) * 33 + d];
        xv[i] = s[V_XC + (tb + i) * 33 + d];
        bm[i] = *(float4*)&s[V_BM + (tb + i) * 20 + ng * 4];
        cm[i] = *(float4*)&s[V_CM + (tb + i) * 20 + ng * 4];
      }
      float yp[4];
      #pragma unroll
      for (int i = 0; i < 4; ++i) {
        float u = dl[i] * xv[i];
        float e0 = __expf(Av.x * dl[i]), e1 = __expf(Av.y * dl[i]);
        float e2 = __expf(Av.z * dl[i]), e3 = __expf(Av.w * dl[i]);
        h0 = fmaf(e0, h0, u * bm[i].x);
        h1 = fmaf(e1, h1, u * bm[i].y);
        h2 = fmaf(e2, h2, u * bm[i].z);
        h3 = fmaf(e3, h3, u * bm[i].w);
        float y = h0 * cm[i].x;
        y = fmaf(h1, cm[i].y, y); y = fmaf(h2, cm[i].z, y); y = fmaf(h3, cm[i].w, y);
        yp[i] = y;
      }
      #pragma unroll
      for (int i = 0; i < 4; ++i) yp[i] += __shfl_xor(yp[i], 1);
      #pragma unroll
      for (int i = 0; i < 4; ++i) yp[i] += __shfl_xor(yp[i], 2);
      float ysel = ng == 0 ? yp[0] : ng == 1 ? yp[1] : ng == 2 ? yp[2] : yp[3];
      s[V_DL + (tb + ng) * 33 + d] = ysel;
    }
  }
  __syncthreads();
  if (act) {
    float y[32];
    #pragma unroll
    for (int d = 0; d < 32; ++d) {
      float z = 0.f;
      #pragma unroll
      for (int j = 0; j < 16; ++j) z = fmaf(s[V_IN + (32 + d) * 16 + j], x16[j], z);
      y[d] = (s[V_DL + tid * 33 + d] + s[V_XC + tid * 33 + d] * s[V_D + d]) * siluf(z);
    }
    float o[16];
    float sk = s[V_SKIP];
    #pragma unroll
    for (int m = 0; m < 16; ++m) {
      float a = 0.f;
      #pragma unroll
      for (int d = 0; d < 32; ++d) a = fmaf(s[V_OUTW + m * 32 + d], y[d], a);
      o[m] = a + sk * x16[m];
    }
    float mu = 0.f;
    #pragma unroll
    for (int m = 0; m < 16; ++m) mu += o[m];
    mu *= (1.f / 16.f);
    float var = 0.f;
    #pragma unroll
    for (int m = 0; m < 16; ++m) { float t = o[m] - mu; var += t * t; }
    var *= (1.f / 16.f);
    float inv = rsqrtf(var + 1e-5f);
    float ln[16];
    #pragma unroll
    for (int m = 0; m < 16; ++m) ln[m] = (o[m] - mu) * inv * s[V_NG + m] + s[V_NB + m];
    #pragma unroll
    for (int m = 0; m < 16; ++m) {
      float a = s[V_PB + m];
      #pragma unroll
      for (int j = 0; j < 16; ++j) a = fmaf(s[V_PW + m * 16 + j], ln[j], a);
      p.out[1835008 + (b * 48 + 32 + m) * 64 + tid] = a;
    }
  }
}

// pass 2: c5 (8 blocks) + cross-sub-chunk combine (32 blocks).
__global__ __launch_bounds__(256) void k_pass2(Params p) {
  __shared__ float s[12564];
  int bid = blockIdx.x, tid = threadIdx.x;
  if (bid < 8) { c5_path(p, s, bid, tid); return; }
  int cb = bid - 8;
  int b = cb >> 2, seq = cb & 3;
  if (tid >= 128) return;
  const int nch[4] = {171, 43, 11, 3};
  const int chf[4] = {0, 171, 214, 225};
  int nsub = nch[seq] * 4;
  int g0 = (b * NCB + chf[seq]) * 4;
  int d = tid >> 3, pr = tid & 7;
  float A0 = -__expf(p.Alog0[d * 16 + pr * 2]);
  float A1 = -__expf(p.Alog0[d * 16 + pr * 2 + 1]);
  unsigned* hu = (unsigned*)p.hloc;
  float h0 = 0.f, h1 = 0.f;
  for (int c0 = 0; c0 < nsub; c0 += 16) {
    unsigned wl[16]; float sdv[16];
    #pragma unroll
    for (int j = 0; j < 16; ++j) {
      int c = c0 + j; size_t g = (size_t)(g0 + c);
      bool v = c < nsub;
      wl[j]  = v ? hu[g * 128 + d * 8 + pr] : 0u;
      sdv[j] = v ? p.sumdelta[g * 16 + d] : 0.f;
    }
    #pragma unroll
    for (int j = 0; j < 16; ++j) {
      int c = c0 + j; size_t g = (size_t)(g0 + c);
      if (c < nsub) hu[g * 128 + d * 8 + pr] = pk(h0, h1);   // h_start, in place
      float e0 = __expf(A0 * sdv[j]), e1 = __expf(A1 * sdv[j]);
      h0 = fmaf(e0, h0, lo16(wl[j]));
      h1 = fmaf(e1, h1, hi16(wl[j]));
    }
  }
}

// pass 3: CPB chunks per block; scan from h_start -> y -> fused epilogue + scatter
__global__ __launch_bounds__(256) void k_pass3(Params p) {
  __shared__ float s[SMEM3];
  int tid = threadIdx.x;
  load_w0(p, s, tid);
  int w = tid >> 6, lane = tid & 63;
  int d = lane >> 2, ng = lane & 3;
  int dh = d >> 1;
  bool dodd = d & 1;
  int t0 = w * SUB;
  const unsigned* su = (const unsigned*)s;
  for (int it = 0; it < CPB; ++it) {
    int cid = blockIdx.x * CPB + it;
    int b, seq, l0, Sa;
    decode_bid(cid, b, seq, l0, Sa);
    __syncthreads();                 // REC/YOF reuse guard
    stage1<34, true>(p, s, b, seq, l0, Sa, tid);
    int gs = cid * 4 + w;
    float4 Av = *(float4*)&s[SW_A + d * 16 + ng * 4];
    const unsigned* hu = (const unsigned*)p.hloc;
    unsigned hw0 = hu[gs * 128 + d * 8 + ng * 2];
    unsigned hw1 = hu[gs * 128 + d * 8 + ng * 2 + 1];
    float h0 = lo16(hw0), h1 = hi16(hw0), h2 = lo16(hw1), h3 = hi16(hw1);
    for (int tile = 0; tile < 8; ++tile) {
      int tb = t0 + tile * 4;
      float dl[4], u[4], b0[4], b1[4], b2[4], b3[4], c0[4], c1[4], c2[4], c3[4];
      #pragma unroll
      for (int i = 0; i < 4; ++i) {
        int base = REC + (tb + i) * 34;
        unsigned wd = su[base + dh];
        unsigned wx = su[base + 8 + dh];
        unsigned wB0 = su[base + 16 + ng * 2];
        unsigned wB1 = su[base + 16 + ng * 2 + 1];
        unsigned wC0 = su[base + 24 + ng * 2];
        unsigned wC1 = su[base + 24 + ng * 2 + 1];
        dl[i] = dodd ? hi16(wd) : lo16(wd);
        u[i] = dl[i] * (dodd ? hi16(wx) : lo16(wx));
        b0[i] = lo16(wB0); b1[i] = hi16(wB0); b2[i] = lo16(wB1); b3[i] = hi16(wB1);
        c0[i] = lo16(wC0); c1[i] = hi16(wC0); c2[i] = lo16(wC1); c3[i] = hi16(wC1);
      }
      float yp[4];
      #pragma unroll
      for (int i = 0; i < 4; ++i) {
        float e0 = __expf(Av.x * dl[i]), e1 = __expf(Av.y * dl[i]);
        float e2 = __expf(Av.z * dl[i]), e3 = __expf(Av.w * dl[i]);
        h0 = fmaf(e0, h0, u[i] * b0[i]);
        h1 = fmaf(e1, h1, u[i] * b1[i]);
        h2 = fmaf(e2, h2, u[i] * b2[i]);
        h3 = fmaf(e3, h3, u[i] * b3[i]);
        float y = h0 * c0[i];
        y = fmaf(h1, c1[i], y); y = fmaf(h2, c2[i], y); y = fmaf(h3, c3[i], y);
        yp[i] = y;
      }
      #pragma unroll
      for (int i = 0; i < 4; ++i) yp[i] += __shfl_xor(yp[i], 1);
      #pragma unroll
      for (int i = 0; i < 4; ++i) yp[i] += __shfl_xor(yp[i], 2);
      float ysel = ng == 0 ? yp[0] : ng == 1 ? yp[1] : ng == 2 ? yp[2] : yp[3];
      s[YOF + (tb + ng) * 16 + d] = ysel;
    }
    __syncthreads();
    if (tid < Sa) {
      int l = l0 + tid;
      float c8[8];
      gather8(p, b, seq, l, c8);
      const unsigned* ru = (const unsigned*)&s[REC + tid * 34];
      float xcv[16];
      #pragma unroll
      for (int j = 0; j < 8; ++j) {
        unsigned wv = ru[8 + j];
        xcv[2*j] = lo16(wv); xcv[2*j + 1] = hi16(wv);
      }
      float y[16];
      #pragma unroll
      for (int i = 0; i < 16; ++i) {
        float z = 0.f;
        #pragma unroll
        for (int j = 0; j < 8; ++j) z = fmaf(s[SW_IN + (16 + i) * 8 + j], c8[j], z);
        y[i] = (s[YOF + tid * 16 + i] + xcv[i] * s[SW_D + i]) * siluf(z);
      }
      float o[8];
      float sk = s[SW_SKIP];
      #pragma unroll
      for (int m = 0; m < 8; ++m) {
        float a = 0.f;
        #pragma unroll
        for (int dd = 0; dd < 16; ++dd) a = fmaf(s[SW_OUTW + m * 16 + dd], y[dd], a);
        o[m] = a + sk * c8[m];
      }
      float mu = 0.f;
      #pragma unroll
      for (int m = 0; m < 8; ++m) mu += o[m];
      mu *= 0.125f;
      float var = 0.f;
      #pragma unroll
      for (int m = 0; m < 8; ++m) { float t = o[m] - mu; var += t * t; }
      var *= 0.125f;
      float inv = rsqrtf(var + 1e-5f);
      float ln[8];
      #pragma unroll
      for (int m = 0; m < 8; ++m) ln[m] = (o[m] - mu) * inv * s[SW_NG + m] + s[SW_NB + m];
      Loc lc = locate(seq, l);
      int obase = outbase(lc.k) + (b * lc.C + lc.ch) * lc.hw + lc.pos;
      #pragma unroll
      for (int m = 0; m < 8; ++m) {
        float a = s[SW_PB + m];
        #pragma unroll
        for (int j = 0; j < 8; ++j) a = fmaf(s[SW_PW + m * 8 + j], ln[j], a);
        p.out[obase + m * lc.hw] = a;
      }
    }
  }
}

extern "C" void kernel_launch(void* const* d_in, const int* in_sizes, int n_in,
                              void* d_out, int out_size, void* d_ws, size_t ws_size,
                              hipStream_t stream) {
  (void)in_sizes; (void)n_in; (void)out_size; (void)ws_size;
  Params p;
  p.t0 = (const float*)d_in[0];  p.t1 = (const float*)d_in[1];
  p.t2 = (const float*)d_in[2];  p.t3 = (const float*)d_in[3];
  p.t4 = (const float*)d_in[4];
  p.in_w0   = (const float*)d_in[5];
  p.conv_w0 = (const float*)d_in[6];
  p.conv_b0 = (const float*)d_in[7];
  p.xproj0  = (const float*)d_in[8];
  p.dtw0    = (const float*)d_in[9];
  p.dtb0    = (const float*)d_in[10];
  p.Alog0   = (const float*)d_in[11];
  p.D0      = (const float*)d_in[12];
  p.outw0   = (const float*)d_in[13];
  p.in_w1   = (const float*)d_in[14];
  p.conv_w1 = (const float*)d_in[15];
  p.conv_b1 = (const float*)d_in[16];
  p.xproj1  = (const float*)d_in[17];
  p.dtw1    = (const float*)d_in[18];
  p.dtb1    = (const float*)d_in[19];
  p.Alog1   = (const float*)d_in[20];
  p.D1      = (const float*)d_in[21];
  p.outw1   = (const float*)d_in[22];
  p.ng  = (const float*)d_in[23];
  p.nb  = (const float*)d_in[24];
  p.pw  = (const float*)d_in[25];
  p.pb  = (const float*)d_in[26];
  p.n1g = (const float*)d_in[27];
  p.n1b = (const float*)d_in[28];
  p.p1w = (const float*)d_in[29];
  p.p1b = (const float*)d_in[30];
  p.skip = (const float*)d_in[31];
  p.out = (float*)d_out;
  float* ws = (float*)d_ws;
  p.hloc     = ws;                               // NSUB*128 u32 words (bf16 pairs)
  p.sumdelta = ws + (size_t)NSUB * 128;          // NSUB*16 f32 (total 4.20 MB)
  k_pass1<<<dim3(NBLK), dim3(256), 0, stream>>>(p);
  k_pass2<<<dim3(40), dim3(256), 0, stream>>>(p);
  k_pass3<<<dim3(NBLK), dim3(256), 0, stream>>>(p);
}

// Round 10
// 359.656 us; speedup vs baseline: 1.6691x; 1.1153x over previous
//
#include <hip/hip_runtime.h>
#include <cmath>

// ---- chunking: SCH=128 tokens/chunk, 4 sub-chunks of 32 (one per wave) ----
// m0 sequences L={21824,5440,1344,320} -> chunks {171,43,11,3} per batch
#define SCH 128
#define SUB 32
#define NCB 228      // chunks per batch: 171+43+11+3
#define NCHUNK 1824  // 8 batches
#define NSUB 7296    // 4*NCHUNK
#define CPB 2        // chunks per block -> 912 blocks, all co-resident at 4 blk/CU
#define NBLK 912
// smem word offsets, m0 path (weights end 1385)
#define SW_IN 0        // 32x8
#define SW_CONVW 256   // 16x4
#define SW_CONVB 320
#define SW_XPROJ 336   // 33x16
#define SW_DTW 864
#define SW_DTB 880
#define SW_A 896       // 16x16  (A = -exp(Alog))
#define SW_D 1152
#define SW_OUTW 1168   // 8x16
#define SW_NG 1296
#define SW_NB 1304
#define SW_PW 1312     // 8x8
#define SW_PB 1376
#define SW_SKIP 1384
// xi (131 rows x 17 fp32, only inside stage1) UNIONs with the packed records:
// record = bf16 pairs [dlp8|xcp8|Bp8|(Cp8)] as u32 words, stride 26 (p1) / 34 (p3)
#define REC 1392
#define XP8 5744       // pass3: packed x8 (131 rows x 4 u32) - epilogue gather removed
#define YOF 6268       // pass3 y region: 128 x 16 f32
#define SMEM1 4720     // 18,880 B
#define SMEM3 8316     // 33,264 B -> 4 blocks/CU by LDS
// c5 (m1) path offsets (inside k_pass2's 12564-word smem)
#define V_IN 0
#define V_CONVW 1024
#define V_CONVB 1152
#define V_XPROJ 1184
#define V_DTW 2240
#define V_DTB 2272
#define V_A 2304
#define V_D 2816
#define V_OUTW 2848
#define V_NG 3360
#define V_NB 3376
#define V_PW 3392
#define V_PB 3648
#define V_SKIP 3664
#define V_XI 3668      // 64x33
#define V_XC 5780      // 64x33
#define V_DL 7892      // 64x33
#define V_BM 10004     // 64x20
#define V_CM 11284     // 64x20 (ends 12564)

struct Params {
  const float *t0, *t1, *t2, *t3, *t4;
  const float *in_w0,*conv_w0,*conv_b0,*xproj0,*dtw0,*dtb0,*Alog0,*D0,*outw0;
  const float *in_w1,*conv_w1,*conv_b1,*xproj1,*dtw1,*dtb1,*Alog1,*D1,*outw1;
  const float *ng,*nb,*pw,*pb,*n1g,*n1b,*p1w,*p1b,*skip;
  float* out;
  float *hloc, *sumdelta;   // hloc = bf16-pair u32 words, 128/sub-chunk (in-place hstart)
};

__device__ __forceinline__ float softplusf(float x) { return x > 20.f ? x : log1pf(__expf(x)); }
__device__ __forceinline__ float siluf(float x) { return x * (1.f / (1.f + __expf(-x))); }
__device__ __forceinline__ unsigned pk(float a, float b) {
  unsigned ua = __float_as_uint(a) + 0x8000u;
  unsigned ub = __float_as_uint(b) + 0x8000u;
  return (ua >> 16) | (ub & 0xFFFF0000u);
}
__device__ __forceinline__ float lo16(unsigned w) { return __uint_as_float(w << 16); }
__device__ __forceinline__ float hi16(unsigned w) { return __uint_as_float(w & 0xFFFF0000u); }

struct Loc { int k, pos, ch, hw, C; };

__device__ __forceinline__ Loc locate(int seq, int l) {
  Loc r;
  if (seq == 0) { r.ch = 0;
    if (l < 16384)      { r.k=0; r.pos=l;        r.hw=16384; r.C=8;  }
    else if (l < 20480) { r.k=1; r.pos=l-16384;  r.hw=4096;  r.C=16; }
    else if (l < 21504) { r.k=2; r.pos=l-20480;  r.hw=1024;  r.C=24; }
    else if (l < 21760) { r.k=3; r.pos=l-21504;  r.hw=256;   r.C=32; }
    else                { r.k=4; r.pos=l-21760;  r.hw=64;    r.C=48; }
  } else if (seq == 1) { r.ch = 8;
    if (l < 4096)       { r.k=1; r.pos=l;        r.hw=4096;  r.C=16; }
    else if (l < 5120)  { r.k=2; r.pos=l-4096;   r.hw=1024;  r.C=24; }
    else if (l < 5376)  { r.k=3; r.pos=l-5120;   r.hw=256;   r.C=32; }
    else                { r.k=4; r.pos=l-5376;   r.hw=64;    r.C=48; }
  } else if (seq == 2) { r.ch = 16;
    if (l < 1024)       { r.k=2; r.pos=l;        r.hw=1024;  r.C=24; }
    else if (l < 1280)  { r.k=3; r.pos=l-1024;   r.hw=256;   r.C=32; }
    else                { r.k=4; r.pos=l-1280;   r.hw=64;    r.C=48; }
  } else { r.ch = 24;
    if (l < 256)        { r.k=3; r.pos=l;        r.hw=256;   r.C=32; }
    else                { r.k=4; r.pos=l-256;    r.hw=64;    r.C=48; }
  }
  return r;
}

__device__ __forceinline__ const float* tsel(const Params& p, int k) {
  switch (k) { case 0: return p.t0; case 1: return p.t1; case 2: return p.t2;
               case 3: return p.t3; default: return p.t4; }
}
// flat offsets of output tensors (with batch dim): total 1859584
__device__ __forceinline__ int outbase(int k) {
  switch (k) { case 0: return 0; case 1: return 1048576; case 2: return 1572864;
               case 3: return 1769472; default: return 1835008; }
}

__device__ __forceinline__ void gather8(const Params& p, int b, int seq, int l, float* c) {
  Loc lc = locate(seq, l);
  const float* t = tsel(p, lc.k);
  int base = (b * lc.C + lc.ch) * lc.hw + lc.pos;
  #pragma unroll
  for (int j = 0; j < 8; ++j) c[j] = t[base + j * lc.hw];
}

__device__ __forceinline__ void decode_bid(int bid, int& b, int& seq, int& l0, int& Sa) {
  b = bid / NCB;
  int r = bid - b * NCB;
  int c, L;
  if (r < 171)      { seq = 0; c = r;       L = 21824; }
  else if (r < 214) { seq = 1; c = r - 171; L = 5440;  }
  else if (r < 225) { seq = 2; c = r - 214; L = 1344;  }
  else              { seq = 3; c = r - 225; L = 320;   }
  l0 = c * SCH;
  int rem = L - l0;
  Sa = rem < SCH ? rem : SCH;   // always 128 or 64
}

__device__ void load_w0(const Params& p, float* s, int tid) {
  for (int i = tid; i < 256; i += 256) s[SW_IN + i] = p.in_w0[i];
  for (int i = tid; i < 64;  i += 256) s[SW_CONVW + i] = p.conv_w0[i];
  for (int i = tid; i < 16;  i += 256) s[SW_CONVB + i] = p.conv_b0[i];
  for (int i = tid; i < 528; i += 256) s[SW_XPROJ + i] = p.xproj0[i];
  for (int i = tid; i < 16;  i += 256) s[SW_DTW + i] = p.dtw0[i];
  for (int i = tid; i < 16;  i += 256) s[SW_DTB + i] = p.dtb0[i];
  for (int i = tid; i < 256; i += 256) s[SW_A + i] = -__expf(p.Alog0[i]);
  for (int i = tid; i < 16;  i += 256) s[SW_D + i] = p.D0[i];
  for (int i = tid; i < 128; i += 256) s[SW_OUTW + i] = p.outw0[i];
  for (int i = tid; i < 8;   i += 256) s[SW_NG + i] = p.ng[i];
  for (int i = tid; i < 8;   i += 256) s[SW_NB + i] = p.nb[i];
  for (int i = tid; i < 64;  i += 256) s[SW_PW + i] = p.pw[i];
  for (int i = tid; i < 8;   i += 256) s[SW_PB + i] = p.pb[i];
  if (tid == 0) s[SW_SKIP] = p.skip[0];
}

// chunk front end: xi fp32 (stride 17) in record region (dead after conv);
// then bf16-pair packed records. Rows >= Sa zeroed => identity scan steps.
// WANT_X8: also stage packed raw x8 (for epilogue - removes its gather).
template <int RSTR, bool WANT_CM, bool WANT_X8>
__device__ void stage1(const Params& p, float* s, int b, int seq, int l0, int Sa, int tid) {
  if (tid < Sa + 3) {                 // rows r <-> token l0-3+r (conv halo)
    int l = l0 - 3 + tid;
    float x8[8];
    if (l >= 0) gather8(p, b, seq, l, x8);
    else {
      #pragma unroll
      for (int j = 0; j < 8; ++j) x8[j] = 0.f;
    }
    #pragma unroll
    for (int i = 0; i < 16; ++i) {
      float a = 0.f;
      #pragma unroll
      for (int j = 0; j < 8; ++j) a = fmaf(s[SW_IN + i * 8 + j], x8[j], a);
      s[REC + tid * 17 + i] = a;
    }
    if (WANT_X8) {
      unsigned* xp = (unsigned*)&s[XP8 + tid * 4];
      #pragma unroll
      for (int q = 0; q < 4; ++q) xp[q] = pk(x8[2*q], x8[2*q + 1]);
    }
  }
  __syncthreads();
  float xc[16];
  float dt = 0.f;
  bool act = tid < Sa;
  if (act) {
    #pragma unroll
    for (int i = 0; i < 16; ++i) {
      float a = s[SW_CONVB + i];
      #pragma unroll
      for (int kk = 0; kk < 4; ++kk)
        a = fmaf(s[SW_CONVW + i * 4 + kk], s[REC + (tid + kk) * 17 + i], a);
      xc[i] = siluf(a);
      dt = fmaf(s[SW_XPROJ + i], xc[i], dt);
    }
  }
  __syncthreads();                    // all xi reads done; region becomes records
  unsigned* ru = (unsigned*)&s[REC + tid * RSTR];
  if (act) {
    #pragma unroll
    for (int j = 0; j < 8; ++j) {
      float a0 = softplusf(fmaf(dt, s[SW_DTW + 2*j],     s[SW_DTB + 2*j]));
      float a1 = softplusf(fmaf(dt, s[SW_DTW + 2*j + 1], s[SW_DTB + 2*j + 1]));
      ru[j] = pk(a0, a1);
    }
    #pragma unroll
    for (int j = 0; j < 8; ++j) ru[8 + j] = pk(xc[2*j], xc[2*j + 1]);
    #pragma unroll
    for (int j = 0; j < 8; ++j) {
      float a0 = 0.f, a1 = 0.f;
      #pragma unroll
      for (int i = 0; i < 16; ++i) {
        a0 = fmaf(s[SW_XPROJ + (1 + 2*j) * 16 + i], xc[i], a0);
        a1 = fmaf(s[SW_XPROJ + (2 + 2*j) * 16 + i], xc[i], a1);
      }
      ru[16 + j] = pk(a0, a1);
    }
    if (WANT_CM) {
      #pragma unroll
      for (int j = 0; j < 8; ++j) {
        float a0 = 0.f, a1 = 0.f;
        #pragma unroll
        for (int i = 0; i < 16; ++i) {
          a0 = fmaf(s[SW_XPROJ + (17 + 2*j) * 16 + i], xc[i], a0);
          a1 = fmaf(s[SW_XPROJ + (18 + 2*j) * 16 + i], xc[i], a1);
        }
        ru[24 + j] = pk(a0, a1);
      }
    }
  } else if (tid < SCH) {             // identity (zero) records for padding rows
    #pragma unroll
    for (int j = 0; j < (WANT_CM ? 32 : 24); ++j) ru[j] = 0u;
  }
  __syncthreads();
}

// pass 1: CPB chunks/block; local scan -> packed h_local + delta sums.
// launch_bounds(256,4): cap 128 VGPR (live set slimmed via u32-staged tiles).
__global__ __launch_bounds__(256, 4) void k_pass1(Params p) {
  __shared__ float s[SMEM1];
  int tid = threadIdx.x;
  load_w0(p, s, tid);
  int w = tid >> 6, lane = tid & 63;
  int d = lane >> 2, ng = lane & 3;
  int dh = d >> 1;
  bool dodd = d & 1;
  int t0 = w * SUB;
  const unsigned* su = (const unsigned*)s;
  for (int it = 0; it < CPB; ++it) {
    int cid = blockIdx.x * CPB + it;
    int b, seq, l0, Sa;
    decode_bid(cid, b, seq, l0, Sa);
    __syncthreads();                 // REC reuse guard (weights ready on it=0)
    stage1<26, false, false>(p, s, b, seq, l0, Sa, tid);
    float4 Av = *(float4*)&s[SW_A + d * 16 + ng * 4];
    float h0 = 0.f, h1 = 0.f, h2 = 0.f, h3 = 0.f, sd = 0.f;
    for (int tile = 0; tile < 8; ++tile) {
      int tb = t0 + tile * 4;
      unsigned wd[4], wx[4], wB0[4], wB1[4];
      #pragma unroll
      for (int i = 0; i < 4; ++i) {
        int base = REC + (tb + i) * 26;
        wd[i] = su[base + dh];
        wx[i] = su[base + 8 + dh];
        wB0[i] = su[base + 16 + ng * 2];
        wB1[i] = su[base + 16 + ng * 2 + 1];
      }
      #pragma unroll
      for (int i = 0; i < 4; ++i) {
        float dl = dodd ? hi16(wd[i]) : lo16(wd[i]);
        float u = dl * (dodd ? hi16(wx[i]) : lo16(wx[i]));
        float e0 = __expf(Av.x * dl), e1 = __expf(Av.y * dl);
        float e2 = __expf(Av.z * dl), e3 = __expf(Av.w * dl);
        h0 = fmaf(e0, h0, u * lo16(wB0[i]));
        h1 = fmaf(e1, h1, u * hi16(wB0[i]));
        h2 = fmaf(e2, h2, u * lo16(wB1[i]));
        h3 = fmaf(e3, h3, u * hi16(wB1[i]));
        sd += dl;
      }
    }
    int gs = cid * 4 + w;
    unsigned* hu = (unsigned*)p.hloc;
    hu[gs * 128 + d * 8 + ng * 2]     = pk(h0, h1);
    hu[gs * 128 + d * 8 + ng * 2 + 1] = pk(h2, h3);
    if (ng == 0) p.sumdelta[(size_t)gs * 16 + d] = sd;
  }
}

// ---- c5 / m1 path (fp32; lives in k_pass2's grid) ----
__device__ void load_w1(const Params& p, float* s, int tid) {
  for (int i = tid; i < 1024; i += 256) s[V_IN + i] = p.in_w1[i];
  for (int i = tid; i < 128;  i += 256) s[V_CONVW + i] = p.conv_w1[i];
  for (int i = tid; i < 32;   i += 256) s[V_CONVB + i] = p.conv_b1[i];
  for (int i = tid; i < 1056; i += 256) s[V_XPROJ + i] = p.xproj1[i];
  for (int i = tid; i < 32;   i += 256) s[V_DTW + i] = p.dtw1[i];
  for (int i = tid; i < 32;   i += 256) s[V_DTB + i] = p.dtb1[i];
  for (int i = tid; i < 512;  i += 256) s[V_A + i] = -__expf(p.Alog1[i]);
  for (int i = tid; i < 32;   i += 256) s[V_D + i] = p.D1[i];
  for (int i = tid; i < 512;  i += 256) s[V_OUTW + i] = p.outw1[i];
  for (int i = tid; i < 16;   i += 256) s[V_NG + i] = p.n1g[i];
  for (int i = tid; i < 16;   i += 256) s[V_NB + i] = p.n1b[i];
  for (int i = tid; i < 256;  i += 256) s[V_PW + i] = p.p1w[i];
  for (int i = tid; i < 16;   i += 256) s[V_PB + i] = p.p1b[i];
  if (tid == 0) s[V_SKIP] = p.skip[0];
}

__device__ void c5_path(const Params& p, float* s, int b, int tid) {
  load_w1(p, s, tid);
  __syncthreads();
  float x16[16];
  bool act = tid < 64;
  if (act) {
    #pragma unroll
    for (int j = 0; j < 16; ++j) x16[j] = p.t4[(b * 48 + 32 + j) * 64 + tid];
    #pragma unroll
    for (int i = 0; i < 32; ++i) {
      float a = 0.f;
      #pragma unroll
      for (int j = 0; j < 16; ++j) a = fmaf(s[V_IN + i * 16 + j], x16[j], a);
      s[V_XI + tid * 33 + i] = a;
    }
  }
  __syncthreads();
  if (act) {
    float xc[32];
    #pragma unroll
    for (int i = 0; i < 32; ++i) {
      float a = s[V_CONVB + i];
      #pragma unroll
      for (int kk = 0; kk < 4; ++kk) {
        int r = tid + kk - 3;
        if (r >= 0) a = fmaf(s[V_CONVW + i * 4 + kk], s[V_XI + r * 33 + i], a);
      }
      xc[i] = siluf(a);
      s[V_XC + tid * 33 + i] = xc[i];
    }
    float dt = 0.f;
    #pragma unroll
    for (int i = 0; i < 32; ++i) dt = fmaf(s[V_XPROJ + i], xc[i], dt);
    #pragma unroll
    for (int n = 0; n < 16; ++n) {
      float a = 0.f, c = 0.f;
      #pragma unroll
      for (int i = 0; i < 32; ++i) {
        a = fmaf(s[V_XPROJ + (1 + n) * 32 + i], xc[i], a);
        c = fmaf(s[V_XPROJ + (17 + n) * 32 + i], xc[i], c);
      }
      s[V_BM + tid * 20 + n] = a;
      s[V_CM + tid * 20 + n] = c;
    }
    #pragma unroll
    for (int d = 0; d < 32; ++d)
      s[V_DL + tid * 33 + d] = softplusf(fmaf(dt, s[V_DTW + d], s[V_DTB + d]));
  }
  __syncthreads();
  if (tid < 128) {
    int d = tid >> 2, ng = tid & 3;
    float4 Av = *(float4*)&s[V_A + d * 16 + ng * 4];
    float h0 = 0.f, h1 = 0.f, h2 = 0.f, h3 = 0.f;
    for (int tile = 0; tile < 16; ++tile) {
      int tb = tile * 4;
      float dl[4], xv[4]; float4 bm[4], cm[4];
      #pragma unroll
      for (int i = 0; i < 4; ++i) {
        dl[i] = s[V_DL + (tb + i) * 33 + d];
        xv[i] = s[V_XC + (tb + i) * 33 + d];
        bm[i] = *(float4*)&s[V_BM + (tb + i) * 20 + ng * 4];
        cm[i] = *(float4*)&s[V_CM + (tb + i) * 20 + ng * 4];
      }
      float yp[4];
      #pragma unroll
      for (int i = 0; i < 4; ++i) {
        float u = dl[i] * xv[i];
        float e0 = __expf(Av.x * dl[i]), e1 = __expf(Av.y * dl[i]);
        float e2 = __expf(Av.z * dl[i]), e3 = __expf(Av.w * dl[i]);
        h0 = fmaf(e0, h0, u * bm[i].x);
        h1 = fmaf(e1, h1, u * bm[i].y);
        h2 = fmaf(e2, h2, u * bm[i].z);
        h3 = fmaf(e3, h3, u * bm[i].w);
        float y = h0 * cm[i].x;
        y = fmaf(h1, cm[i].y, y); y = fmaf(h2, cm[i].z, y); y = fmaf(h3, cm[i].w, y);
        yp[i] = y;
      }
      #pragma unroll
      for (int i = 0; i < 4; ++i) yp[i] += __shfl_xor(yp[i], 1);
      #pragma unroll
      for (int i = 0; i < 4; ++i) yp[i] += __shfl_xor(yp[i], 2);
      float ysel = ng == 0 ? yp[0] : ng == 1 ? yp[1] : ng == 2 ? yp[2] : yp[3];
      s[V_DL + (tb + ng) * 33 + d] = ysel;
    }
  }
  __syncthreads();
  if (act) {
    float y[32];
    #pragma unroll
    for (int d = 0; d < 32; ++d) {
      float z = 0.f;
      #pragma unroll
      for (int j = 0; j < 16; ++j) z = fmaf(s[V_IN + (32 + d) * 16 + j], x16[j], z);
      y[d] = (s[V_DL + tid * 33 + d] + s[V_XC + tid * 33 + d] * s[V_D + d]) * siluf(z);
    }
    float o[16];
    float sk = s[V_SKIP];
    #pragma unroll
    for (int m = 0; m < 16; ++m) {
      float a = 0.f;
      #pragma unroll
      for (int d = 0; d < 32; ++d) a = fmaf(s[V_OUTW + m * 32 + d], y[d], a);
      o[m] = a + sk * x16[m];
    }
    float mu = 0.f;
    #pragma unroll
    for (int m = 0; m < 16; ++m) mu += o[m];
    mu *= (1.f / 16.f);
    float var = 0.f;
    #pragma unroll
    for (int m = 0; m < 16; ++m) { float t = o[m] - mu; var += t * t; }
    var *= (1.f / 16.f);
    float inv = rsqrtf(var + 1e-5f);
    float ln[16];
    #pragma unroll
    for (int m = 0; m < 16; ++m) ln[m] = (o[m] - mu) * inv * s[V_NG + m] + s[V_NB + m];
    #pragma unroll
    for (int m = 0; m < 16; ++m) {
      float a = s[V_PB + m];
      #pragma unroll
      for (int j = 0; j < 16; ++j) a = fmaf(s[V_PW + m * 16 + j], ln[j], a);
      p.out[1835008 + (b * 48 + 32 + m) * 64 + tid] = a;
    }
  }
}

// pass 2: c5 (8 blocks) + cross-sub-chunk combine (32 blocks).
__global__ __launch_bounds__(256) void k_pass2(Params p) {
  __shared__ float s[12564];
  int bid = blockIdx.x, tid = threadIdx.x;
  if (bid < 8) { c5_path(p, s, bid, tid); return; }
  int cb = bid - 8;
  int b = cb >> 2, seq = cb & 3;
  if (tid >= 128) return;
  const int nch[4] = {171, 43, 11, 3};
  const int chf[4] = {0, 171, 214, 225};
  int nsub = nch[seq] * 4;
  int g0 = (b * NCB + chf[seq]) * 4;
  int d = tid >> 3, pr = tid & 7;
  float A0 = -__expf(p.Alog0[d * 16 + pr * 2]);
  float A1 = -__expf(p.Alog0[d * 16 + pr * 2 + 1]);
  unsigned* hu = (unsigned*)p.hloc;
  float h0 = 0.f, h1 = 0.f;
  for (int c0 = 0; c0 < nsub; c0 += 16) {
    unsigned wl[16]; float sdv[16];
    #pragma unroll
    for (int j = 0; j < 16; ++j) {
      int c = c0 + j; size_t g = (size_t)(g0 + c);
      bool v = c < nsub;
      wl[j]  = v ? hu[g * 128 + d * 8 + pr] : 0u;
      sdv[j] = v ? p.sumdelta[g * 16 + d] : 0.f;
    }
    #pragma unroll
    for (int j = 0; j < 16; ++j) {
      int c = c0 + j; size_t g = (size_t)(g0 + c);
      if (c < nsub) hu[g * 128 + d * 8 + pr] = pk(h0, h1);   // h_start, in place
      float e0 = __expf(A0 * sdv[j]), e1 = __expf(A1 * sdv[j]);
      h0 = fmaf(e0, h0, lo16(wl[j]));
      h1 = fmaf(e1, h1, hi16(wl[j]));
    }
  }
}

// pass 3: CPB chunks/block; scan from h_start -> y -> slim fused epilogue.
// launch_bounds(256,4): cap 128 VGPR (u32-staged tiles, per-d-pair o-accum,
// x8 from LDS - no second gather).
__global__ __launch_bounds__(256, 4) void k_pass3(Params p) {
  __shared__ float s[SMEM3];
  int tid = threadIdx.x;
  load_w0(p, s, tid);
  int w = tid >> 6, lane = tid & 63;
  int d = lane >> 2, ng = lane & 3;
  int dh = d >> 1;
  bool dodd = d & 1;
  int t0 = w * SUB;
  const unsigned* su = (const unsigned*)s;
  for (int it = 0; it < CPB; ++it) {
    int cid = blockIdx.x * CPB + it;
    int b, seq, l0, Sa;
    decode_bid(cid, b, seq, l0, Sa);
    __syncthreads();                 // REC/XP8/YOF reuse guard
    stage1<34, true, true>(p, s, b, seq, l0, Sa, tid);
    int gs = cid * 4 + w;
    float4 Av = *(float4*)&s[SW_A + d * 16 + ng * 4];
    const unsigned* hu = (const unsigned*)p.hloc;
    unsigned hw0 = hu[gs * 128 + d * 8 + ng * 2];
    unsigned hw1 = hu[gs * 128 + d * 8 + ng * 2 + 1];
    float h0 = lo16(hw0), h1 = hi16(hw0), h2 = lo16(hw1), h3 = hi16(hw1);
    for (int tile = 0; tile < 8; ++tile) {
      int tb = t0 + tile * 4;
      unsigned wd[4], wx[4], wB0[4], wB1[4], wC0[4], wC1[4];
      #pragma unroll
      for (int i = 0; i < 4; ++i) {
        int base = REC + (tb + i) * 34;
        wd[i] = su[base + dh];
        wx[i] = su[base + 8 + dh];
        wB0[i] = su[base + 16 + ng * 2];
        wB1[i] = su[base + 16 + ng * 2 + 1];
        wC0[i] = su[base + 24 + ng * 2];
        wC1[i] = su[base + 24 + ng * 2 + 1];
      }
      float yp[4];
      #pragma unroll
      for (int i = 0; i < 4; ++i) {
        float dl = dodd ? hi16(wd[i]) : lo16(wd[i]);
        float u = dl * (dodd ? hi16(wx[i]) : lo16(wx[i]));
        float e0 = __expf(Av.x * dl), e1 = __expf(Av.y * dl);
        float e2 = __expf(Av.z * dl), e3 = __expf(Av.w * dl);
        h0 = fmaf(e0, h0, u * lo16(wB0[i]));
        h1 = fmaf(e1, h1, u * hi16(wB0[i]));
        h2 = fmaf(e2, h2, u * lo16(wB1[i]));
        h3 = fmaf(e3, h3, u * hi16(wB1[i]));
        float y = h0 * lo16(wC0[i]);
        y = fmaf(h1, hi16(wC0[i]), y);
        y = fmaf(h2, lo16(wC1[i]), y);
        y = fmaf(h3, hi16(wC1[i]), y);
        yp[i] = y;
      }
      #pragma unroll
      for (int i = 0; i < 4; ++i) yp[i] += __shfl_xor(yp[i], 1);
      #pragma unroll
      for (int i = 0; i < 4; ++i) yp[i] += __shfl_xor(yp[i], 2);
      float ysel = ng == 0 ? yp[0] : ng == 1 ? yp[1] : ng == 2 ? yp[2] : yp[3];
      s[YOF + (tb + ng) * 16 + d] = ysel;
    }
    __syncthreads();
    if (tid < Sa) {
      // c8 from LDS-staged packed x8 (row tid+3) - no global gather here
      const unsigned* xp = (const unsigned*)&s[XP8 + (tid + 3) * 4];
      float c8[8];
      #pragma unroll
      for (int q = 0; q < 4; ++q) { c8[2*q] = lo16(xp[q]); c8[2*q+1] = hi16(xp[q]); }
      const unsigned* ru = (const unsigned*)&s[REC + tid * 34];
      float o[8];
      float sk = s[SW_SKIP];
      #pragma unroll
      for (int m = 0; m < 8; ++m) o[m] = sk * c8[m];
      #pragma unroll
      for (int j = 0; j < 8; ++j) {           // d-pair 2j, 2j+1
        unsigned wv = ru[8 + j];
        float z0 = 0.f, z1 = 0.f;
        #pragma unroll
        for (int k = 0; k < 8; ++k) {
          z0 = fmaf(s[SW_IN + (16 + 2*j) * 8 + k], c8[k], z0);
          z1 = fmaf(s[SW_IN + (17 + 2*j) * 8 + k], c8[k], z1);
        }
        float y0 = (s[YOF + tid * 16 + 2*j]     + lo16(wv) * s[SW_D + 2*j])     * siluf(z0);
        float y1 = (s[YOF + tid * 16 + 2*j + 1] + hi16(wv) * s[SW_D + 2*j + 1]) * siluf(z1);
        #pragma unroll
        for (int m = 0; m < 8; ++m) {
          o[m] = fmaf(s[SW_OUTW + m * 16 + 2*j], y0, o[m]);
          o[m] = fmaf(s[SW_OUTW + m * 16 + 2*j + 1], y1, o[m]);
        }
      }
      float mu = 0.f;
      #pragma unroll
      for (int m = 0; m < 8; ++m) mu += o[m];
      mu *= 0.125f;
      float var = 0.f;
      #pragma unroll
      for (int m = 0; m < 8; ++m) { float t = o[m] - mu; var += t * t; }
      var *= 0.125f;
      float inv = rsqrtf(var + 1e-5f);
      #pragma unroll
      for (int m = 0; m < 8; ++m) o[m] = (o[m] - mu) * inv * s[SW_NG + m] + s[SW_NB + m];
      Loc lc = locate(seq, l0 + tid);
      int obase = outbase(lc.k) + (b * lc.C + lc.ch) * lc.hw + lc.pos;
      #pragma unroll
      for (int m = 0; m < 8; ++m) {
        float a = s[SW_PB + m];
        #pragma unroll
        for (int j = 0; j < 8; ++j) a = fmaf(s[SW_PW + m * 8 + j], o[j], a);
        p.out[obase + m * lc.hw] = a;
      }
    }
  }
}

extern "C" void kernel_launch(void* const* d_in, const int* in_sizes, int n_in,
                              void* d_out, int out_size, void* d_ws, size_t ws_size,
                              hipStream_t stream) {
  (void)in_sizes; (void)n_in; (void)out_size; (void)ws_size;
  Params p;
  p.t0 = (const float*)d_in[0];  p.t1 = (const float*)d_in[1];
  p.t2 = (const float*)d_in[2];  p.t3 = (const float*)d_in[3];
  p.t4 = (const float*)d_in[4];
  p.in_w0   = (const float*)d_in[5];
  p.conv_w0 = (const float*)d_in[6];
  p.conv_b0 = (const float*)d_in[7];
  p.xproj0  = (const float*)d_in[8];
  p.dtw0    = (const float*)d_in[9];
  p.dtb0    = (const float*)d_in[10];
  p.Alog0   = (const float*)d_in[11];
  p.D0      = (const float*)d_in[12];
  p.outw0   = (const float*)d_in[13];
  p.in_w1   = (const float*)d_in[14];
  p.conv_w1 = (const float*)d_in[15];
  p.conv_b1 = (const float*)d_in[16];
  p.xproj1  = (const float*)d_in[17];
  p.dtw1    = (const float*)d_in[18];
  p.dtb1    = (const float*)d_in[19];
  p.Alog1   = (const float*)d_in[20];
  p.D1      = (const float*)d_in[21];
  p.outw1   = (const float*)d_in[22];
  p.ng  = (const float*)d_in[23];
  p.nb  = (const float*)d_in[24];
  p.pw  = (const float*)d_in[25];
  p.pb  = (const float*)d_in[26];
  p.n1g = (const float*)d_in[27];
  p.n1b = (const float*)d_in[28];
  p.p1w = (const float*)d_in[29];
  p.p1b = (const float*)d_in[30];
  p.skip = (const float*)d_in[31];
  p.out = (float*)d_out;
  float* ws = (float*)d_ws;
  p.hloc     = ws;                               // NSUB*128 u32 words (bf16 pairs)
  p.sumdelta = ws + (size_t)NSUB * 128;          // NSUB*16 f32 (total 4.20 MB)
  k_pass1<<<dim3(NBLK), dim3(256), 0, stream>>>(p);
  k_pass2<<<dim3(40), dim3(256), 0, stream>>>(p);
  k_pass3<<<dim3(NBLK), dim3(256), 0, stream>>>(p);
}